// Round 2
// baseline (578.079 us; speedup 1.0000x reference)
//
#include <hip/hip_runtime.h>

// Submanifold sparse conv via offset-grouped pair lists ("rulebook"):
//  1. memset dense voxel grid (130^3 int) to sentinel
//  2. build_grid: atomicMin(grid[key], i)  (ref resolves dup voxels to MIN idx)
//     + zero the 27 per-offset pair counters
//  3. build_pairs: thread=(pt,o): 1 grid lookup; present & o!=13 -> append (pt,j)
//  4. center_conv: out[pt,:] = feat[grid[key(pt)]] @ W[13]   (plain store)
//  5. offset_conv: per-offset blocks, W[o] held in 32 VGPRs/lane, stream pairs,
//     float4 feature broadcasts, atomicAdd accumulate.
// Weight is never re-read per pair from cache -> kills the 4KB/pair L1 floor.

#define GRID_B 130
#define GRID_CELLS (GRID_B * GRID_B * GRID_B)   // 2,197,000
#define C_IN 32
#define C_OUT 32
#define N_CAP 16384                              // per-offset list capacity (~4.7k expected, 170 sigma)

__global__ void build_grid_kernel(const int* __restrict__ pos,
                                  int* __restrict__ grid,
                                  int* __restrict__ cnt, int n) {
    int i = blockIdx.x * blockDim.x + threadIdx.x;
    if (i < 27) cnt[i] = 0;                      // counters used by next dispatch
    if (i >= n) return;
    int x = pos[3 * i + 0] + 1;
    int y = pos[3 * i + 1] + 1;
    int z = pos[3 * i + 2] + 1;
    atomicMin(&grid[(x * GRID_B + y) * GRID_B + z], i);
}

__global__ void build_pairs_kernel(const int* __restrict__ pos,
                                   const int* __restrict__ grid,
                                   int* __restrict__ cnt,
                                   int2* __restrict__ lists, int n) {
    int tid = blockIdx.x * blockDim.x + threadIdx.x;
    if (tid >= n * 27) return;
    int pt = tid / 27;
    int o = tid - pt * 27;
    if (o == 13) return;                         // center handled implicitly
    // off[o] = (o/9 - 1, (o/3)%3 - 1, o%3 - 1)  [meshgrid ij order]
    int x = pos[3 * pt + 0] + (o / 9) - 1 + 1;
    int y = pos[3 * pt + 1] + ((o / 3) % 3) - 1 + 1;
    int z = pos[3 * pt + 2] + (o % 3) - 1 + 1;
    int j = grid[(x * GRID_B + y) * GRID_B + z];
    if (j < n) {
        int idx = atomicAdd(&cnt[o], 1);
        if (idx < N_CAP) lists[o * N_CAP + idx] = make_int2(pt, j);
    }
}

__global__ void center_conv_kernel(const float* __restrict__ feat,
                                   const int* __restrict__ pos,
                                   const float* __restrict__ w,
                                   const int* __restrict__ grid,
                                   float* __restrict__ out, int n) {
    int pt = blockIdx.x * 8 + (threadIdx.x >> 5);
    if (pt >= n) return;
    int cout = threadIdx.x & 31;
    float wreg[32];
    #pragma unroll
    for (int c = 0; c < 32; ++c) wreg[c] = w[13 * 1024 + c * 32 + cout];  // coalesced, once
    int x = pos[3 * pt + 0] + 1;
    int y = pos[3 * pt + 1] + 1;
    int z = pos[3 * pt + 2] + 1;
    int j = grid[(x * GRID_B + y) * GRID_B + z];  // own voxel always occupied (min-dup idx)
    const float4* __restrict__ f4 = (const float4*)(feat + j * C_IN);
    float acc = 0.0f;
    #pragma unroll
    for (int k = 0; k < 8; ++k) {
        float4 v = f4[k];
        acc = fmaf(v.x, wreg[4 * k + 0], acc);
        acc = fmaf(v.y, wreg[4 * k + 1], acc);
        acc = fmaf(v.z, wreg[4 * k + 2], acc);
        acc = fmaf(v.w, wreg[4 * k + 3], acc);
    }
    out[pt * C_OUT + cout] = acc;                // plain store: zeroes-out poison too
}

// block = 256 thr = 4 waves; each wave streams 16 pairs (2 at a time in half-waves)
__global__ void offset_conv_kernel(const float* __restrict__ feat,
                                   const float* __restrict__ w,
                                   const int* __restrict__ cnt,
                                   const int2* __restrict__ lists,
                                   float* __restrict__ out, int n) {
    int oy = blockIdx.y;
    int o = oy + (oy >= 13 ? 1 : 0);             // skip center
    int count = cnt[o];
    if (count > N_CAP) count = N_CAP;
    int block_base = blockIdx.x * 64;
    if (block_base >= count) return;             // fast exit before weight preload

    int wave = threadIdx.x >> 6;                 // 0..3
    int lane = threadIdx.x & 63;
    int cout = lane & 31;
    int half = lane >> 5;

    float wreg[32];
    #pragma unroll
    for (int c = 0; c < 32; ++c) wreg[c] = w[o * 1024 + c * 32 + cout];

    int wbase = block_base + wave * 16;
    int nloc = count - wbase;
    if (nloc > 16) nloc = 16;

    int2 e = make_int2(0, 0);
    if (lane < 16 && wbase + lane < count) e = lists[o * N_CAP + wbase + lane];

    for (int i = 0; 2 * i < nloc; ++i) {
        int src = 2 * i + half;                  // half-wave -> its pair
        int pt = __shfl(e.x, src);
        int j  = __shfl(e.y, src);
        if (src < nloc) {
            const float4* __restrict__ f4 = (const float4*)(feat + j * C_IN);
            float acc = 0.0f;
            #pragma unroll
            for (int k = 0; k < 8; ++k) {
                float4 v = f4[k];
                acc = fmaf(v.x, wreg[4 * k + 0], acc);
                acc = fmaf(v.y, wreg[4 * k + 1], acc);
                acc = fmaf(v.z, wreg[4 * k + 2], acc);
                acc = fmaf(v.w, wreg[4 * k + 3], acc);
            }
            atomicAdd(&out[pt * C_OUT + cout], acc);
        }
    }
}

extern "C" void kernel_launch(void* const* d_in, const int* in_sizes, int n_in,
                              void* d_out, int out_size, void* d_ws, size_t ws_size,
                              hipStream_t stream) {
    const float* features = (const float*)d_in[0];
    const int*   positions = (const int*)d_in[1];
    const float* weight = (const float*)d_in[2];
    float* out = (float*)d_out;
    const int n = in_sizes[0] / C_IN;            // 100000

    // ws layout: grid | 32 counters | 27*N_CAP int2 lists  (~12.33 MB total)
    int* grid = (int*)d_ws;
    int* cnt = grid + GRID_CELLS;
    int2* lists = (int2*)(cnt + 32);             // 8B-aligned

    hipMemsetAsync(grid, 0x7F, (size_t)GRID_CELLS * sizeof(int), stream);

    build_grid_kernel<<<(n + 255) / 256, 256, 0, stream>>>(positions, grid, cnt, n);

    build_pairs_kernel<<<(n * 27 + 255) / 256, 256, 0, stream>>>(positions, grid, cnt,
                                                                 lists, n);

    center_conv_kernel<<<(n + 7) / 8, 256, 0, stream>>>(features, positions, weight,
                                                        grid, out, n);

    offset_conv_kernel<<<dim3(N_CAP / 64, 26), 256, 0, stream>>>(features, weight, cnt,
                                                                 lists, out, n);
}

// Round 3
// 434.166 us; speedup vs baseline: 1.3315x; 1.3315x over previous
//
#include <hip/hip_runtime.h>

// Submanifold sparse conv, fused persistent-kernel version.
//   Dispatch 1 (init): zero grid (2.2M ints) + barrier counter + padded pair counters.
//   Dispatch 2 (fused, 512 blocks x 256 thr, co-resident):
//     P2: build voxel grid:  atomicMax(grid[key], n - i)  (min-index dup resolution)
//     B1
//     P3: each point probes its 27 neighbor voxels (27 loads issued together for MLP);
//         o==13 -> rep[pt]; else wave-aggregated append (pt, j) to list[o]
//         (1 leader atomic per wave per offset; counters padded to 128B lines)
//     B2
//     P4: center: out[pt*32+cout] = feat[rep[pt]] . W[13]  (plain agent store; inits out)
//     B3
//     P5: drain 26 lists: chunked flat work-list, W[o] column in 32 VGPRs, half-wave
//         per pair, float4 feature broadcasts, atomicAdd into out (distinct addresses).
// R2 lesson: per-lane same-line atomics serialize at ~4.8 cyc/op through ONE L2 slice
// (451 us). Wave aggregation + line-padding removes that. ~15 us/dispatch gap tax ->
// fuse to 2 dispatches with in-kernel grid barriers (all cross-block traffic uses
// agent-scope atomics; per-XCD L2s are not coherent).

#define GRID_B 130
#define GRID_CELLS 2197000            // 130^3
#define C 32
#define N_CAP 8192                    // per-offset list capacity (expected ~4.5k)
#define NBLK 512
#define NTHR 256
#define NTHREADS (NBLK * NTHR)        // 131072
#define CNT_STRIDE 32                 // ints: 128B per counter -> distinct L2 lines

// ws layout in int units:
#define BAR_I   2197024               // grid padded to 32-int boundary
#define CNT_I   2197056               // 27 * 32 ints
#define REP_I   2197920
#define LISTS_I 2297920               // (REP_I + 100000); byte off 9191680, 8B-aligned
#define ZERO_ULL ((CNT_I + 27 * CNT_STRIDE + 1) / 2)   // zero grid+bar+cnt: 1098960 ull

#define AR __ATOMIC_RELAXED
#define SCOPE __HIP_MEMORY_SCOPE_AGENT

__global__ void init_kernel(unsigned long long* __restrict__ ws8) {
    int step = gridDim.x * blockDim.x;
    for (int i = blockIdx.x * blockDim.x + threadIdx.x; i < ZERO_ULL; i += step)
        __hip_atomic_store(&ws8[i], 0ull, AR, SCOPE);
}

__device__ __forceinline__ void gbar(unsigned* bar, unsigned k) {
    __threadfence();
    __syncthreads();
    if (threadIdx.x == 0) {
        __hip_atomic_fetch_add(bar, 1u, __ATOMIC_ACQ_REL, SCOPE);
        const unsigned target = k * (unsigned)NBLK;
        while (__hip_atomic_load(bar, __ATOMIC_ACQUIRE, SCOPE) < target)
            __builtin_amdgcn_s_sleep(8);
    }
    __syncthreads();
}

__global__ __launch_bounds__(NTHR, 2)
void fused_kernel(const float* __restrict__ feat,
                  const int* __restrict__ pos,
                  const float* __restrict__ w,
                  int* __restrict__ ws_i,
                  float* __restrict__ out, int n) {
    int* grid = ws_i;
    unsigned* bar = (unsigned*)(ws_i + BAR_I);
    int* cnt = ws_i + CNT_I;
    int* rep = ws_i + REP_I;
    unsigned long long* lists = (unsigned long long*)(ws_i + LISTS_I);

    const int tid = blockIdx.x * NTHR + threadIdx.x;
    const int lane = threadIdx.x & 63;
    const bool active = tid < n;

    int px = 0, py = 0, pz = 0;
    if (active) {
        px = pos[3 * tid + 0] + 1;
        py = pos[3 * tid + 1] + 1;
        pz = pos[3 * tid + 2] + 1;
        int key = (px * GRID_B + py) * GRID_B + pz;
        __hip_atomic_fetch_max(&grid[key], n - tid, AR, SCOPE);   // max(n-i) == min i
    }

    gbar(bar, 1);

    // ---- P3: probe 27 neighbors (loads first, for memory-level parallelism) ----
    int v[27];
    #pragma unroll
    for (int o = 0; o < 27; ++o) {
        int x = px + o / 9 - 1;
        int y = py + (o / 3) % 3 - 1;
        int z = pz + o % 3 - 1;
        int key = (x * GRID_B + y) * GRID_B + z;
        v[o] = active ? __hip_atomic_load(&grid[key], AR, SCOPE) : 0;
    }
    #pragma unroll
    for (int o = 0; o < 27; ++o) {
        if (o == 13) {
            if (active) __hip_atomic_store(&rep[tid], n - v[13], AR, SCOPE);
            continue;
        }
        bool hit = active && (v[o] >= 1);
        unsigned long long m = __ballot(hit);
        if (m != 0ull) {
            int ldr = __ffsll(m) - 1;
            int cw = __popcll(m);
            unsigned base = 0;
            if (lane == ldr)
                base = __hip_atomic_fetch_add((unsigned*)&cnt[o * CNT_STRIDE],
                                              (unsigned)cw, AR, SCOPE);
            base = (unsigned)__shfl((int)base, ldr);
            if (hit) {
                int slot = (int)base + (int)__popcll(m & ((1ull << lane) - 1ull));
                if (slot < N_CAP) {
                    unsigned long long e =
                        ((unsigned long long)(unsigned)(n - v[o]) << 32) | (unsigned)tid;
                    __hip_atomic_store(&lists[o * N_CAP + slot], e, AR, SCOPE);
                }
            }
        }
    }

    gbar(bar, 2);

    // ---- P4: center contribution (plain store initializes out) ----
    {
        const int cout = threadIdx.x & 31;     // constant across iterations
        float wreg[32];
        #pragma unroll
        for (int c = 0; c < 32; ++c) wreg[c] = w[13 * 1024 + c * 32 + cout];
        const int n32 = n * 32;
        for (int it = 0; it < 25; ++it) {
            int u = tid + it * NTHREADS;
            if (u < n32) {
                int pt = u >> 5;
                int r = __hip_atomic_load(&rep[pt], AR, SCOPE);
                const float4* __restrict__ f4 = (const float4*)(feat + r * C);
                float acc = 0.0f;
                #pragma unroll
                for (int k = 0; k < 8; ++k) {
                    float4 fv = f4[k];
                    acc = fmaf(fv.x, wreg[4 * k + 0], acc);
                    acc = fmaf(fv.y, wreg[4 * k + 1], acc);
                    acc = fmaf(fv.z, wreg[4 * k + 2], acc);
                    acc = fmaf(fv.w, wreg[4 * k + 3], acc);
                }
                __hip_atomic_store(&out[u], acc, AR, SCOPE);
            }
        }
    }

    gbar(bar, 3);

    // ---- P5: drain the 26 offset lists ----
    {
        int counts[27];
        int total_chunks = 0;
        #pragma unroll
        for (int o = 0; o < 27; ++o) {
            int c = (o == 13) ? 0
                              : __hip_atomic_load(&cnt[o * CNT_STRIDE], AR, SCOPE);
            c = min(c, N_CAP);
            counts[o] = c;
            total_chunks += (c + 15) >> 4;
        }
        const int wave_id = tid >> 6;
        const int n_waves = NTHREADS >> 6;   // 2048
        const int cout = lane & 31;
        const int half = lane >> 5;

        for (int f = wave_id; f < total_chunks; f += n_waves) {
            int o = 0, rem = f;
            while (rem >= ((counts[o] + 15) >> 4)) {   // wave-uniform scan
                rem -= (counts[o] + 15) >> 4;
                ++o;
            }
            int cbase = rem * 16;
            int npair = min(16, counts[o] - cbase);

            float wreg[32];
            #pragma unroll
            for (int c = 0; c < 32; ++c) wreg[c] = w[o * 1024 + c * 32 + cout];

            unsigned long long e = 0ull;
            if (lane < npair)
                e = __hip_atomic_load(&lists[o * N_CAP + cbase + lane], AR, SCOPE);
            int pt_i = (int)(e & 0xffffffffu);
            int j_i  = (int)(e >> 32);

            for (int i = 0; 2 * i < npair; ++i) {
                int src = 2 * i + half;
                int pt = __shfl(pt_i, src);
                int j  = __shfl(j_i, src);
                if (src < npair) {
                    const float4* __restrict__ f4 = (const float4*)(feat + j * C);
                    float acc = 0.0f;
                    #pragma unroll
                    for (int k = 0; k < 8; ++k) {
                        float4 fv = f4[k];
                        acc = fmaf(fv.x, wreg[4 * k + 0], acc);
                        acc = fmaf(fv.y, wreg[4 * k + 1], acc);
                        acc = fmaf(fv.z, wreg[4 * k + 2], acc);
                        acc = fmaf(fv.w, wreg[4 * k + 3], acc);
                    }
                    atomicAdd(&out[pt * C + cout], acc);
                }
            }
        }
    }
}

extern "C" void kernel_launch(void* const* d_in, const int* in_sizes, int n_in,
                              void* d_out, int out_size, void* d_ws, size_t ws_size,
                              hipStream_t stream) {
    const float* features = (const float*)d_in[0];
    const int*   positions = (const int*)d_in[1];
    const float* weight = (const float*)d_in[2];
    float* out = (float*)d_out;
    const int n = in_sizes[0] / C;     // 100000

    init_kernel<<<NBLK, NTHR, 0, stream>>>((unsigned long long*)d_ws);
    fused_kernel<<<NBLK, NTHR, 0, stream>>>(features, positions, weight,
                                            (int*)d_ws, out, n);
}